// Round 3
// baseline (1036.946 us; speedup 1.0000x reference)
//
#include <hip/hip_runtime.h>
#include <hip/hip_bf16.h>

#define TNODES 262144
#define TEDGES 1048576
#define TSAMP  65536

typedef __attribute__((ext_vector_type(8))) short short8;
typedef __attribute__((ext_vector_type(4))) float f32x4;

__device__ __forceinline__ __hip_bfloat16 f2bf(float v) { return __float2bfloat16(v); }
__device__ __forceinline__ float bf2f(__hip_bfloat16 v) { return __bfloat162float(v); }
__device__ __forceinline__ float sigf(float x) { return 1.0f / (1.0f + __expf(-x)); }
__device__ __forceinline__ float tanh_f(float x) {
    x = fminf(fmaxf(x, -15.0f), 15.0f);
    float e = __expf(2.0f * x);
    return (e - 1.0f) / (e + 1.0f);
}

// ---------------------------------------------------------------------------
// Transpose [W_ih; W_hh] (fp32, each 128x512 row-major) -> Wt bf16 [512][256]
// ---------------------------------------------------------------------------
__global__ __launch_bounds__(256) void transpose_wt(
    const float* __restrict__ Wih, const float* __restrict__ Whh,
    __hip_bfloat16* __restrict__ Wt)
{
    int i = blockIdx.x * 256 + threadIdx.x;   // 131072 total
    int n = i >> 8, k = i & 255;
    float v = (k < 128) ? Wih[k * 512 + n] : Whh[(k - 128) * 512 + n];
    Wt[i] = f2bf(v);
}

// ---------------------------------------------------------------------------
// Edge MLP (67 -> 64, relu) + atomic scatter into agg[TNODES][64]  (all fp32)
// ---------------------------------------------------------------------------
__global__ __launch_bounds__(256) void edge_kernel(
    const float* __restrict__ x, const int* __restrict__ ei,
    const float* __restrict__ ea, const float* __restrict__ Wm,
    const float* __restrict__ bm, float* __restrict__ agg)
{
    __shared__ float sW[67 * 64];
    __shared__ float sB[64];
    __shared__ __align__(16) float sIn[4][272];   // per wave, [k][t] transposed
    int tid = threadIdx.x;
    for (int i = tid; i < 67 * 64; i += 256) sW[i] = Wm[i];
    if (tid < 64) sB[tid] = bm[tid];
    __syncthreads();
    int wave = tid >> 6, lane = tid & 63;
    int gwave = blockIdx.x * 4 + wave;            // 4096 waves, 256 edges each
    float* in = sIn[wave];
    for (int it = 0; it < 64; ++it) {
        int e0 = gwave * 256 + it * 4;
        for (int s = lane; s < 272; s += 64) {
            int k = s >> 2, t = s & 3;
            int e = e0 + t;
            float v = 0.0f;
            if (k < 26)      v = x[ei[e] * 26 + k];
            else if (k < 52) v = x[ei[TEDGES + e] * 26 + (k - 26)];
            else if (k < 67) v = ea[e * 15 + (k - 52)];
            in[s] = v;
        }
        __syncthreads();   // uniform trip count across all 4 waves
        float b = sB[lane];
        float a0 = b, a1 = b, a2 = b, a3 = b;
        for (int k = 0; k < 67; ++k) {
            float4 iv = *(const float4*)&in[k * 4];
            float  w  = sW[k * 64 + lane];
            a0 = fmaf(iv.x, w, a0); a1 = fmaf(iv.y, w, a1);
            a2 = fmaf(iv.z, w, a2); a3 = fmaf(iv.w, w, a3);
        }
        int d0 = ei[TEDGES + e0 + 0], d1 = ei[TEDGES + e0 + 1];
        int d2 = ei[TEDGES + e0 + 2], d3 = ei[TEDGES + e0 + 3];
        atomicAdd(&agg[d0 * 64 + lane], fmaxf(a0, 0.0f));
        atomicAdd(&agg[d1 * 64 + lane], fmaxf(a1, 0.0f));
        atomicAdd(&agg[d2 * 64 + lane], fmaxf(a2, 0.0f));
        atomicAdd(&agg[d3 * 64 + lane], fmaxf(a3, 0.0f));
    }
}

// ---------------------------------------------------------------------------
// Node MLP (90 -> 64, relu) on SAMPLED rows only -> node_conv fp32 (d_out)
// ---------------------------------------------------------------------------
__global__ __launch_bounds__(256) void conv_kernel(
    const float* __restrict__ x, const float* __restrict__ agg,
    const int* __restrict__ samp, const float* __restrict__ Wn,
    const float* __restrict__ bn, float* __restrict__ out_nc)
{
    __shared__ float sW[90 * 64];
    __shared__ float sB[64];
    __shared__ __align__(16) float sIn[4][360];
    int tid = threadIdx.x;
    for (int i = tid; i < 90 * 64; i += 256) sW[i] = Wn[i];
    if (tid < 64) sB[tid] = bn[tid];
    __syncthreads();
    int wave = tid >> 6, lane = tid & 63;
    int gwave = blockIdx.x * 4 + wave;            // 2048 waves, 32 rows each
    for (int it = 0; it < 8; ++it) {
        int r0 = gwave * 32 + it * 4;
        for (int s = lane; s < 360; s += 64) {
            int k = s >> 2, t = s & 3;
            int node = samp[r0 + t];
            float v;
            if (k < 26) v = x[node * 26 + k];
            else        v = agg[node * 64 + (k - 26)];
            sIn[wave][s] = v;
        }
        __syncthreads();
        float b = sB[lane];
        float a0 = b, a1 = b, a2 = b, a3 = b;
        for (int k = 0; k < 90; ++k) {
            float4 iv = *(const float4*)&sIn[wave][k * 4];
            float  w  = sW[k * 64 + lane];
            a0 = fmaf(iv.x, w, a0); a1 = fmaf(iv.y, w, a1);
            a2 = fmaf(iv.z, w, a2); a3 = fmaf(iv.w, w, a3);
        }
        out_nc[(r0 + 0) * 64 + lane] = fmaxf(a0, 0.0f);
        out_nc[(r0 + 1) * 64 + lane] = fmaxf(a1, 0.0f);
        out_nc[(r0 + 2) * 64 + lane] = fmaxf(a2, 0.0f);
        out_nc[(r0 + 3) * 64 + lane] = fmaxf(a3, 0.0f);
    }
}

// ---------------------------------------------------------------------------
// Encoder (fp32 compute): X = relu(nc_masked @ W_enc + b), H0 = relu(nc @ W_enc + b)
// Writes A0 = [X | H0], A1 = [ .. | H0]  as bf16 rows of 256 (MFMA staging)
// ---------------------------------------------------------------------------
__global__ __launch_bounds__(256) void enc_kernel(
    const float* __restrict__ nc, const float* __restrict__ gm,
    const float* __restrict__ We, const float* __restrict__ be,
    __hip_bfloat16* __restrict__ A0, __hip_bfloat16* __restrict__ A1)
{
    __shared__ float sW[64 * 128];
    __shared__ float sB[128];
    __shared__ __align__(16) float sIn[4][128];
    __shared__ float sGm[4][20];
    int tid = threadIdx.x;
    for (int i = tid; i < 64 * 128; i += 256) sW[i] = We[i];
    if (tid < 128) sB[tid] = be[tid];
    __syncthreads();
    int wave = tid >> 6, lane = tid & 63;
    int gwave = blockIdx.x * 4 + wave;            // 4096 waves, 16 rows each
    for (int it = 0; it < 8; ++it) {
        int r0 = gwave * 16 + it * 2;
        for (int s = lane; s < 128; s += 64) {
            int k = s >> 1, t = s & 1;
            sIn[wave][s] = nc[(r0 + t) * 64 + k];
        }
        if (lane < 20) {
            int t = lane / 10, c = lane % 10;
            sGm[wave][lane] = gm[((r0 + t) >> 10) * 10 + c];
        }
        __syncthreads();
        float bA = sB[lane], bB = sB[lane + 64];
        float h0a = bA, h0b = bB, h1a = bA, h1b = bB;
        float x0a = bA, x0b = bB, x1a = bA, x1b = bB;
        for (int k = 0; k < 64; ++k) {
            float2 iv = *(const float2*)&sIn[wave][k * 2];
            float wA = sW[k * 128 + lane], wB = sW[k * 128 + lane + 64];
            float g0 = (k >= 54) ? sGm[wave][k - 54]      : iv.x;
            float g1 = (k >= 54) ? sGm[wave][10 + k - 54] : iv.y;
            h0a = fmaf(iv.x, wA, h0a); h0b = fmaf(iv.x, wB, h0b);
            h1a = fmaf(iv.y, wA, h1a); h1b = fmaf(iv.y, wB, h1b);
            x0a = fmaf(g0, wA, x0a);   x0b = fmaf(g0, wB, x0b);
            x1a = fmaf(g1, wA, x1a);   x1b = fmaf(g1, wB, x1b);
        }
        int r = r0;
        float hA = fmaxf(h0a, 0.0f), hB = fmaxf(h0b, 0.0f);
        A0[r * 256 + lane]        = f2bf(fmaxf(x0a, 0.0f));
        A0[r * 256 + 64 + lane]   = f2bf(fmaxf(x0b, 0.0f));
        A0[r * 256 + 128 + lane]  = f2bf(hA);
        A0[r * 256 + 192 + lane]  = f2bf(hB);
        A1[r * 256 + 128 + lane]  = f2bf(hA);
        A1[r * 256 + 192 + lane]  = f2bf(hB);
        r = r0 + 1;
        hA = fmaxf(h1a, 0.0f); hB = fmaxf(h1b, 0.0f);
        A0[r * 256 + lane]        = f2bf(fmaxf(x1a, 0.0f));
        A0[r * 256 + 64 + lane]   = f2bf(fmaxf(x1b, 0.0f));
        A0[r * 256 + 128 + lane]  = f2bf(hA);
        A0[r * 256 + 192 + lane]  = f2bf(hB);
        A1[r * 256 + 128 + lane]  = f2bf(hA);
        A1[r * 256 + 192 + lane]  = f2bf(hB);
    }
}

// ---------------------------------------------------------------------------
// LSTM cell: g = A(65536x256,bf16) @ Wt^T(bf16) + b_ih + b_hh; gates -> h,c (fp32)
// MFMA 16x16x32 bf16. Block = 64 rows x full 512 cols (epilogue lane-local).
// stage 0: Anext[0:128] = h1 with cols 118..127 <- gm   (A = A0, Anext = A1)
// stage 1: Anext = [h2 | c2]                            (A = A1, Anext = A2)
// ---------------------------------------------------------------------------
__global__ __launch_bounds__(256) void lstm_kernel(
    const __hip_bfloat16* __restrict__ A, const __hip_bfloat16* __restrict__ Wt,
    const float* __restrict__ bih, const float* __restrict__ bhh,
    const float* __restrict__ gm,
    float* __restrict__ h_out, float* __restrict__ c_out,
    __hip_bfloat16* __restrict__ Anext, int stage)
{
    __shared__ __align__(16) __hip_bfloat16 sA[64 * 40];     // stride 40 pads banks
    __shared__ __align__(16) __hip_bfloat16 sBt[512 * 40];
    int tid = threadIdx.x, wave = tid >> 6, lane = tid & 63;
    int rowBlk = blockIdx.x * 64;
    f32x4 acc[32];
#pragma unroll
    for (int t = 0; t < 32; ++t) acc[t] = (f32x4){0.0f, 0.0f, 0.0f, 0.0f};

    int ar = tid >> 2, ac = (tid & 3) << 3;
    for (int k0 = 0; k0 < 256; k0 += 32) {
        *(uint4*)&sA[ar * 40 + ac] = *(const uint4*)&A[(rowBlk + ar) * 256 + k0 + ac];
#pragma unroll
        for (int rep = 0; rep < 8; ++rep) {
            int idx = rep * 256 + tid;
            int n = idx >> 2, c = (idx & 3) << 3;
            *(uint4*)&sBt[n * 40 + c] = *(const uint4*)&Wt[n * 256 + k0 + c];
        }
        __syncthreads();
        short8 af = *(const short8*)&sA[(wave * 16 + (lane & 15)) * 40 + ((lane >> 4) << 3)];
#pragma unroll
        for (int t = 0; t < 32; ++t) {
            short8 bfr = *(const short8*)&sBt[((t << 4) + (lane & 15)) * 40 + ((lane >> 4) << 3)];
            acc[t] = __builtin_amdgcn_mfma_f32_16x16x32_bf16(af, bfr, acc[t], 0, 0, 0);
        }
        __syncthreads();
    }

    int col = lane & 15, quad = lane >> 4;
#pragma unroll
    for (int t = 0; t < 8; ++t) {
        int j = t * 16 + col;
        float B0 = bih[j]       + bhh[j];
        float B1 = bih[j + 128] + bhh[j + 128];
        float B2 = bih[j + 256] + bhh[j + 256];
        float B3 = bih[j + 384] + bhh[j + 384];
#pragma unroll
        for (int i = 0; i < 4; ++i) {
            int row = rowBlk + wave * 16 + quad * 4 + i;
            float gi = acc[t][i]      + B0;
            float gf = acc[t + 8][i]  + B1;
            float gg = acc[t + 16][i] + B2;
            float go = acc[t + 24][i] + B3;
            float cin = bf2f(A[row * 256 + 128 + j]);
            float cn = sigf(gf) * cin + sigf(gi) * tanh_f(gg);
            float hn = sigf(go) * tanh_f(cn);
            h_out[row * 128 + j] = hn;
            c_out[row * 128 + j] = cn;
            if (stage == 0) {
                float hg = (j >= 118) ? gm[(row >> 10) * 10 + (j - 118)] : hn;
                Anext[row * 256 + j] = f2bf(hg);
            } else {
                Anext[row * 256 + j]       = f2bf(hn);
                Anext[row * 256 + 128 + j] = f2bf(cn);
            }
        }
    }
}

// ---------------------------------------------------------------------------
// Decoder (fp32): y = relu([h2|c2] @ W_d1 + b_d1) @ W_d2 + b_d2
// ---------------------------------------------------------------------------
__global__ __launch_bounds__(256) void dec_kernel(
    const __hip_bfloat16* __restrict__ A2, const float* __restrict__ Wd1,
    const float* __restrict__ bd1, const float* __restrict__ Wd2,
    const float* __restrict__ bd2, float* __restrict__ y)
{
    __shared__ float sW1[256 * 64];
    __shared__ float sB1[64];
    __shared__ __align__(16) float sA[4][256];
    int tid = threadIdx.x;
    for (int i = tid; i < 256 * 64; i += 256) sW1[i] = Wd1[i];
    if (tid < 64) sB1[tid] = bd1[tid];
    __syncthreads();
    int wave = tid >> 6, lane = tid & 63;
    int gwave = blockIdx.x * 4 + wave;            // 4096 waves, 16 rows each
    float w2[6];
#pragma unroll
    for (int i = 0; i < 6; ++i) w2[i] = Wd2[lane * 6 + i];
    for (int it = 0; it < 16; ++it) {
        int r = gwave * 16 + it;
#pragma unroll
        for (int q = 0; q < 4; ++q) sA[wave][lane * 4 + q] = bf2f(A2[r * 256 + lane * 4 + q]);
        __syncthreads();
        float acc = sB1[lane];
        for (int k = 0; k < 256; k += 4) {
            float4 iv = *(const float4*)&sA[wave][k];
            acc = fmaf(iv.x, sW1[(k + 0) * 64 + lane], acc);
            acc = fmaf(iv.y, sW1[(k + 1) * 64 + lane], acc);
            acc = fmaf(iv.z, sW1[(k + 2) * 64 + lane], acc);
            acc = fmaf(iv.w, sW1[(k + 3) * 64 + lane], acc);
        }
        float d1 = fmaxf(acc, 0.0f);
        float v0 = d1 * w2[0], v1 = d1 * w2[1], v2 = d1 * w2[2];
        float v3 = d1 * w2[3], v4 = d1 * w2[4], v5 = d1 * w2[5];
#pragma unroll
        for (int off = 32; off >= 1; off >>= 1) {
            v0 += __shfl_xor(v0, off); v1 += __shfl_xor(v1, off);
            v2 += __shfl_xor(v2, off); v3 += __shfl_xor(v3, off);
            v4 += __shfl_xor(v4, off); v5 += __shfl_xor(v5, off);
        }
        if (lane == 0) {
            y[r * 6 + 0] = v0 + bd2[0];
            y[r * 6 + 1] = v1 + bd2[1];
            y[r * 6 + 2] = v2 + bd2[2];
            y[r * 6 + 3] = v3 + bd2[3];
            y[r * 6 + 4] = v4 + bd2[4];
            y[r * 6 + 5] = v5 + bd2[5];
        }
    }
}

// ---------------------------------------------------------------------------
// Workspace layout (total 67,633,152 B ≈ 64.5 MiB):
//   [0, 256K)        : Wt0 bf16        [256K, 512K) : Wt1 bf16
//   [512K, 512K+64M) : agg fp32 262144x64           -- dead after conv
//   [512K, +32M)     : A0 bf16 65536x256 (aliases agg; used after conv)
//                      A2 reuses A0 after lstm stage 0
//   [512K+32M, +64M) : A1 bf16 65536x256
// ---------------------------------------------------------------------------
extern "C" void kernel_launch(void* const* d_in, const int* in_sizes, int n_in,
                              void* d_out, int out_size, void* d_ws, size_t ws_size,
                              hipStream_t stream)
{
    const float* x    = (const float*)d_in[0];
    const int*   ei   = (const int*)d_in[1];
    const float* ea   = (const float*)d_in[2];
    const int*   samp = (const int*)d_in[3];
    const float* gm   = (const float*)d_in[4];
    const float* Wm   = (const float*)d_in[5];
    const float* bm   = (const float*)d_in[6];
    const float* Wn   = (const float*)d_in[7];
    const float* bn   = (const float*)d_in[8];
    const float* We   = (const float*)d_in[9];
    const float* be   = (const float*)d_in[10];
    const float* Wih0 = (const float*)d_in[11];
    const float* Whh0 = (const float*)d_in[12];
    const float* bih0 = (const float*)d_in[13];
    const float* bhh0 = (const float*)d_in[14];
    const float* Wih1 = (const float*)d_in[15];
    const float* Whh1 = (const float*)d_in[16];
    const float* bih1 = (const float*)d_in[17];
    const float* bhh1 = (const float*)d_in[18];
    const float* Wd1  = (const float*)d_in[19];
    const float* bd1  = (const float*)d_in[20];
    const float* Wd2  = (const float*)d_in[21];
    const float* bd2  = (const float*)d_in[22];

    char* ws = (char*)d_ws;
    __hip_bfloat16* Wt0 = (__hip_bfloat16*)ws;                  // 256 KiB
    __hip_bfloat16* Wt1 = (__hip_bfloat16*)(ws + 262144);       // 256 KiB
    float*          agg = (float*)(ws + 524288);                // 64 MiB
    __hip_bfloat16* A0  = (__hip_bfloat16*)(ws + 524288);       // 32 MiB (after conv)
    __hip_bfloat16* A2  = (__hip_bfloat16*)(ws + 524288);       // reuses A0 after lstm0
    __hip_bfloat16* A1  = (__hip_bfloat16*)(ws + 524288 + 33554432);

    float* out  = (float*)d_out;
    float* o_nc = out;                 // 65536*64
    float* o_h1 = out + 4194304;       // 65536*128
    float* o_c1 = out + 12582912;
    float* o_h2 = out + 20971520;
    float* o_c2 = out + 29360128;
    float* o_y  = out + 37748736;      // 65536*6

    hipMemsetAsync(agg, 0, 67108864, stream);
    transpose_wt<<<512, 256, 0, stream>>>(Wih0, Whh0, Wt0);
    transpose_wt<<<512, 256, 0, stream>>>(Wih1, Whh1, Wt1);
    edge_kernel<<<1024, 256, 0, stream>>>(x, ei, ea, Wm, bm, agg);
    conv_kernel<<<512, 256, 0, stream>>>(x, agg, samp, Wn, bn, o_nc);
    enc_kernel<<<1024, 256, 0, stream>>>(o_nc, gm, We, be, A0, A1);
    lstm_kernel<<<1024, 256, 0, stream>>>(A0, Wt0, bih0, bhh0, gm, o_h1, o_c1, A1, 0);
    lstm_kernel<<<1024, 256, 0, stream>>>(A1, Wt1, bih1, bhh1, gm, o_h2, o_c2, A2, 1);
    dec_kernel<<<1024, 256, 0, stream>>>(A2, Wd1, bd1, Wd2, bd2, o_y);
}

// Round 4
// 896.612 us; speedup vs baseline: 1.1565x; 1.1565x over previous
//
#include <hip/hip_runtime.h>
#include <hip/hip_bf16.h>

#define TNODES 262144
#define TEDGES 1048576
#define TSAMP  65536

typedef __attribute__((ext_vector_type(8))) short short8;
typedef __attribute__((ext_vector_type(4))) float f32x4;

__device__ __forceinline__ __hip_bfloat16 f2bf(float v) { return __float2bfloat16(v); }
__device__ __forceinline__ float bf2f(__hip_bfloat16 v) { return __bfloat162float(v); }
__device__ __forceinline__ short bfbits(float v) {
    __hip_bfloat16 b = __float2bfloat16(v);
    return *(short*)&b;
}
__device__ __forceinline__ float sigf(float x) { return 1.0f / (1.0f + __expf(-x)); }
__device__ __forceinline__ float tanh_f(float x) {
    x = fminf(fmaxf(x, -15.0f), 15.0f);
    float e = __expf(2.0f * x);
    return (e - 1.0f) / (e + 1.0f);
}

// ---------------------------------------------------------------------------
// Transpose [W_ih; W_hh] (fp32, each 128x512 row-major) -> Wt bf16 [512][256]
// ---------------------------------------------------------------------------
__global__ __launch_bounds__(256) void transpose_wt(
    const float* __restrict__ Wih, const float* __restrict__ Whh,
    __hip_bfloat16* __restrict__ Wt)
{
    int i = blockIdx.x * 256 + threadIdx.x;   // 131072 total
    int n = i >> 8, k = i & 255;
    float v = (k < 128) ? Wih[k * 512 + n] : Whh[(k - 128) * 512 + n];
    Wt[i] = f2bf(v);
}

// ---------------------------------------------------------------------------
// Edge MLP (67 -> 64, relu) + atomic scatter into agg[TNODES][64]
// Direct-gather MFMA: A-frag gathered straight from global (no LDS/barriers).
// Wave = 16 edges/iter x 8 iters = 128 edges. K padded to 96 (3 k-steps).
// A[m=lane&15][k=quad*8+j]; C: col=lane&15 (out ch), row=quad*4+reg (edge).
// ---------------------------------------------------------------------------
__global__ __launch_bounds__(256) void edge_kernel(
    const float* __restrict__ x, const int* __restrict__ ei,
    const float* __restrict__ ea, const float* __restrict__ Wm,
    const float* __restrict__ bm, float* __restrict__ agg)
{
    int tid = threadIdx.x, wave = tid >> 6, lane = tid & 63;
    int col = lane & 15, quad = lane >> 4;
    long gwave = (long)blockIdx.x * 4 + wave;     // 8192 waves, 128 edges each

    // B-fragments in registers: b[t][s] holds W[k=32s+quad*8+j][n=16t+col]
    short8 bfr[4][3];
#pragma unroll
    for (int t = 0; t < 4; ++t)
#pragma unroll
        for (int s = 0; s < 3; ++s)
#pragma unroll
            for (int j = 0; j < 8; ++j) {
                int k = 32 * s + quad * 8 + j;
                int n = 16 * t + col;
                float v = (k < 67) ? Wm[k * 64 + n] : 0.0f;
                bfr[t][s][j] = bfbits(v);
            }
    float biasv[4];
#pragma unroll
    for (int t = 0; t < 4; ++t) biasv[t] = bm[t * 16 + col];

    for (int it = 0; it < 8; ++it) {
        long e0 = gwave * 128 + it * 16;
        // gather A-fragments for edge m = col
        long e = e0 + col;
        int si = ei[e], di = ei[TEDGES + e];
        const float* xs  = x + (long)si * 26;
        const float* xd  = x + (long)di * 26;
        const float* eap = ea + e * 15;
        short8 afr[3];
#pragma unroll
        for (int s = 0; s < 3; ++s)
#pragma unroll
            for (int j = 0; j < 8; ++j) {
                int k = 32 * s + quad * 8 + j;
                const float* p = (k < 26) ? (xs + k)
                               : ((k < 52) ? (xd + (k - 26)) : (eap + (k - 52)));
                p = (k < 67) ? p : xs;          // safe dummy address
                float v = *p;
                v = (k < 67) ? v : 0.0f;
                afr[s][j] = bfbits(v);
            }
        // dst rows for this lane's C rows
        int drow[4];
#pragma unroll
        for (int i = 0; i < 4; ++i) drow[i] = ei[TEDGES + e0 + quad * 4 + i];

        f32x4 acc[4];
#pragma unroll
        for (int t = 0; t < 4; ++t) acc[t] = (f32x4){0.0f, 0.0f, 0.0f, 0.0f};
#pragma unroll
        for (int s = 0; s < 3; ++s)
#pragma unroll
            for (int t = 0; t < 4; ++t)
                acc[t] = __builtin_amdgcn_mfma_f32_16x16x32_bf16(afr[s], bfr[t][s], acc[t], 0, 0, 0);

#pragma unroll
        for (int t = 0; t < 4; ++t) {
            int n = t * 16 + col;
#pragma unroll
            for (int i = 0; i < 4; ++i) {
                float v = fmaxf(acc[t][i] + biasv[t], 0.0f);
                atomicAdd(&agg[(long)drow[i] * 64 + n], v);
            }
        }
    }
}

// ---------------------------------------------------------------------------
// Node MLP (90 -> 64, relu) on SAMPLED rows only -> node_conv fp32 (d_out)
// ---------------------------------------------------------------------------
__global__ __launch_bounds__(256) void conv_kernel(
    const float* __restrict__ x, const float* __restrict__ agg,
    const int* __restrict__ samp, const float* __restrict__ Wn,
    const float* __restrict__ bn, float* __restrict__ out_nc)
{
    __shared__ float sW[90 * 64];
    __shared__ float sB[64];
    __shared__ __align__(16) float sIn[4][360];
    int tid = threadIdx.x;
    for (int i = tid; i < 90 * 64; i += 256) sW[i] = Wn[i];
    if (tid < 64) sB[tid] = bn[tid];
    __syncthreads();
    int wave = tid >> 6, lane = tid & 63;
    int gwave = blockIdx.x * 4 + wave;            // 2048 waves, 32 rows each
    for (int it = 0; it < 8; ++it) {
        int r0 = gwave * 32 + it * 4;
        for (int s = lane; s < 360; s += 64) {
            int k = s >> 2, t = s & 3;
            int node = samp[r0 + t];
            float v;
            if (k < 26) v = x[node * 26 + k];
            else        v = agg[node * 64 + (k - 26)];
            sIn[wave][s] = v;
        }
        __syncthreads();
        float b = sB[lane];
        float a0 = b, a1 = b, a2 = b, a3 = b;
        for (int k = 0; k < 90; ++k) {
            float4 iv = *(const float4*)&sIn[wave][k * 4];
            float  w  = sW[k * 64 + lane];
            a0 = fmaf(iv.x, w, a0); a1 = fmaf(iv.y, w, a1);
            a2 = fmaf(iv.z, w, a2); a3 = fmaf(iv.w, w, a3);
        }
        out_nc[(r0 + 0) * 64 + lane] = fmaxf(a0, 0.0f);
        out_nc[(r0 + 1) * 64 + lane] = fmaxf(a1, 0.0f);
        out_nc[(r0 + 2) * 64 + lane] = fmaxf(a2, 0.0f);
        out_nc[(r0 + 3) * 64 + lane] = fmaxf(a3, 0.0f);
    }
}

// ---------------------------------------------------------------------------
// Encoder (fp32 compute): X = relu(nc_masked @ W_enc + b), H0 = relu(nc @ W_enc + b)
// Writes A0 = [X | H0], A1 = [ .. | H0]  as bf16 rows of 256 (MFMA staging)
// ---------------------------------------------------------------------------
__global__ __launch_bounds__(256) void enc_kernel(
    const float* __restrict__ nc, const float* __restrict__ gm,
    const float* __restrict__ We, const float* __restrict__ be,
    __hip_bfloat16* __restrict__ A0, __hip_bfloat16* __restrict__ A1)
{
    __shared__ float sW[64 * 128];
    __shared__ float sB[128];
    __shared__ __align__(16) float sIn[4][128];
    __shared__ float sGm[4][20];
    int tid = threadIdx.x;
    for (int i = tid; i < 64 * 128; i += 256) sW[i] = We[i];
    if (tid < 128) sB[tid] = be[tid];
    __syncthreads();
    int wave = tid >> 6, lane = tid & 63;
    int gwave = blockIdx.x * 4 + wave;            // 4096 waves, 16 rows each
    for (int it = 0; it < 8; ++it) {
        int r0 = gwave * 16 + it * 2;
        for (int s = lane; s < 128; s += 64) {
            int k = s >> 1, t = s & 1;
            sIn[wave][s] = nc[(r0 + t) * 64 + k];
        }
        if (lane < 20) {
            int t = lane / 10, c = lane % 10;
            sGm[wave][lane] = gm[((r0 + t) >> 10) * 10 + c];
        }
        __syncthreads();
        float bA = sB[lane], bB = sB[lane + 64];
        float h0a = bA, h0b = bB, h1a = bA, h1b = bB;
        float x0a = bA, x0b = bB, x1a = bA, x1b = bB;
        for (int k = 0; k < 64; ++k) {
            float2 iv = *(const float2*)&sIn[wave][k * 2];
            float wA = sW[k * 128 + lane], wB = sW[k * 128 + lane + 64];
            float g0 = (k >= 54) ? sGm[wave][k - 54]      : iv.x;
            float g1 = (k >= 54) ? sGm[wave][10 + k - 54] : iv.y;
            h0a = fmaf(iv.x, wA, h0a); h0b = fmaf(iv.x, wB, h0b);
            h1a = fmaf(iv.y, wA, h1a); h1b = fmaf(iv.y, wB, h1b);
            x0a = fmaf(g0, wA, x0a);   x0b = fmaf(g0, wB, x0b);
            x1a = fmaf(g1, wA, x1a);   x1b = fmaf(g1, wB, x1b);
        }
        int r = r0;
        float hA = fmaxf(h0a, 0.0f), hB = fmaxf(h0b, 0.0f);
        A0[r * 256 + lane]        = f2bf(fmaxf(x0a, 0.0f));
        A0[r * 256 + 64 + lane]   = f2bf(fmaxf(x0b, 0.0f));
        A0[r * 256 + 128 + lane]  = f2bf(hA);
        A0[r * 256 + 192 + lane]  = f2bf(hB);
        A1[r * 256 + 128 + lane]  = f2bf(hA);
        A1[r * 256 + 192 + lane]  = f2bf(hB);
        r = r0 + 1;
        hA = fmaxf(h1a, 0.0f); hB = fmaxf(h1b, 0.0f);
        A0[r * 256 + lane]        = f2bf(fmaxf(x1a, 0.0f));
        A0[r * 256 + 64 + lane]   = f2bf(fmaxf(x1b, 0.0f));
        A0[r * 256 + 128 + lane]  = f2bf(hA);
        A0[r * 256 + 192 + lane]  = f2bf(hB);
        A1[r * 256 + 128 + lane]  = f2bf(hA);
        A1[r * 256 + 192 + lane]  = f2bf(hB);
    }
}

// ---------------------------------------------------------------------------
// LSTM cell: g = A(65536x256,bf16) @ Wt^T(bf16) + b_ih + b_hh; gates -> h,c (fp32)
// MFMA 16x16x32 bf16. Block = 64 rows x full 512 cols (epilogue lane-local).
// stage 0: Anext[0:128] = h1 with cols 118..127 <- gm   (A = A0, Anext = A1)
// stage 1: Anext = [h2 | c2]                            (A = A1, Anext = A2)
// ---------------------------------------------------------------------------
__global__ __launch_bounds__(256) void lstm_kernel(
    const __hip_bfloat16* __restrict__ A, const __hip_bfloat16* __restrict__ Wt,
    const float* __restrict__ bih, const float* __restrict__ bhh,
    const float* __restrict__ gm,
    float* __restrict__ h_out, float* __restrict__ c_out,
    __hip_bfloat16* __restrict__ Anext, int stage)
{
    __shared__ __align__(16) __hip_bfloat16 sA[64 * 40];     // stride 40 pads banks
    __shared__ __align__(16) __hip_bfloat16 sBt[512 * 40];
    int tid = threadIdx.x, wave = tid >> 6, lane = tid & 63;
    int rowBlk = blockIdx.x * 64;
    f32x4 acc[32];
#pragma unroll
    for (int t = 0; t < 32; ++t) acc[t] = (f32x4){0.0f, 0.0f, 0.0f, 0.0f};

    int ar = tid >> 2, ac = (tid & 3) << 3;
    for (int k0 = 0; k0 < 256; k0 += 32) {
        *(uint4*)&sA[ar * 40 + ac] = *(const uint4*)&A[(rowBlk + ar) * 256 + k0 + ac];
#pragma unroll
        for (int rep = 0; rep < 8; ++rep) {
            int idx = rep * 256 + tid;
            int n = idx >> 2, c = (idx & 3) << 3;
            *(uint4*)&sBt[n * 40 + c] = *(const uint4*)&Wt[n * 256 + k0 + c];
        }
        __syncthreads();
        short8 af = *(const short8*)&sA[(wave * 16 + (lane & 15)) * 40 + ((lane >> 4) << 3)];
#pragma unroll
        for (int t = 0; t < 32; ++t) {
            short8 bfr = *(const short8*)&sBt[((t << 4) + (lane & 15)) * 40 + ((lane >> 4) << 3)];
            acc[t] = __builtin_amdgcn_mfma_f32_16x16x32_bf16(af, bfr, acc[t], 0, 0, 0);
        }
        __syncthreads();
    }

    int col = lane & 15, quad = lane >> 4;
#pragma unroll
    for (int t = 0; t < 8; ++t) {
        int j = t * 16 + col;
        float B0 = bih[j]       + bhh[j];
        float B1 = bih[j + 128] + bhh[j + 128];
        float B2 = bih[j + 256] + bhh[j + 256];
        float B3 = bih[j + 384] + bhh[j + 384];
#pragma unroll
        for (int i = 0; i < 4; ++i) {
            int row = rowBlk + wave * 16 + quad * 4 + i;
            float gi = acc[t][i]      + B0;
            float gf = acc[t + 8][i]  + B1;
            float gg = acc[t + 16][i] + B2;
            float go = acc[t + 24][i] + B3;
            float cin = bf2f(A[row * 256 + 128 + j]);
            float cn = sigf(gf) * cin + sigf(gi) * tanh_f(gg);
            float hn = sigf(go) * tanh_f(cn);
            h_out[row * 128 + j] = hn;
            c_out[row * 128 + j] = cn;
            if (stage == 0) {
                float hg = (j >= 118) ? gm[(row >> 10) * 10 + (j - 118)] : hn;
                Anext[row * 256 + j] = f2bf(hg);
            } else {
                Anext[row * 256 + j]       = f2bf(hn);
                Anext[row * 256 + 128 + j] = f2bf(cn);
            }
        }
    }
}

// ---------------------------------------------------------------------------
// Decoder (fp32): y = relu([h2|c2] @ W_d1 + b_d1) @ W_d2 + b_d2
// ---------------------------------------------------------------------------
__global__ __launch_bounds__(256) void dec_kernel(
    const __hip_bfloat16* __restrict__ A2, const float* __restrict__ Wd1,
    const float* __restrict__ bd1, const float* __restrict__ Wd2,
    const float* __restrict__ bd2, float* __restrict__ y)
{
    __shared__ float sW1[256 * 64];
    __shared__ float sB1[64];
    __shared__ __align__(16) float sA[4][256];
    int tid = threadIdx.x;
    for (int i = tid; i < 256 * 64; i += 256) sW1[i] = Wd1[i];
    if (tid < 64) sB1[tid] = bd1[tid];
    __syncthreads();
    int wave = tid >> 6, lane = tid & 63;
    int gwave = blockIdx.x * 4 + wave;            // 4096 waves, 16 rows each
    float w2[6];
#pragma unroll
    for (int i = 0; i < 6; ++i) w2[i] = Wd2[lane * 6 + i];
    for (int it = 0; it < 16; ++it) {
        int r = gwave * 16 + it;
#pragma unroll
        for (int q = 0; q < 4; ++q) sA[wave][lane * 4 + q] = bf2f(A2[r * 256 + lane * 4 + q]);
        __syncthreads();
        float acc = sB1[lane];
        for (int k = 0; k < 256; k += 4) {
            float4 iv = *(const float4*)&sA[wave][k];
            acc = fmaf(iv.x, sW1[(k + 0) * 64 + lane], acc);
            acc = fmaf(iv.y, sW1[(k + 1) * 64 + lane], acc);
            acc = fmaf(iv.z, sW1[(k + 2) * 64 + lane], acc);
            acc = fmaf(iv.w, sW1[(k + 3) * 64 + lane], acc);
        }
        float d1 = fmaxf(acc, 0.0f);
        float v0 = d1 * w2[0], v1 = d1 * w2[1], v2 = d1 * w2[2];
        float v3 = d1 * w2[3], v4 = d1 * w2[4], v5 = d1 * w2[5];
#pragma unroll
        for (int off = 32; off >= 1; off >>= 1) {
            v0 += __shfl_xor(v0, off); v1 += __shfl_xor(v1, off);
            v2 += __shfl_xor(v2, off); v3 += __shfl_xor(v3, off);
            v4 += __shfl_xor(v4, off); v5 += __shfl_xor(v5, off);
        }
        if (lane == 0) {
            y[r * 6 + 0] = v0 + bd2[0];
            y[r * 6 + 1] = v1 + bd2[1];
            y[r * 6 + 2] = v2 + bd2[2];
            y[r * 6 + 3] = v3 + bd2[3];
            y[r * 6 + 4] = v4 + bd2[4];
            y[r * 6 + 5] = v5 + bd2[5];
        }
    }
}

// ---------------------------------------------------------------------------
// Workspace layout (total ≈ 64.5 MiB):
//   [0, 256K)        : Wt0 bf16        [256K, 512K) : Wt1 bf16
//   [512K, 512K+64M) : agg fp32 262144x64           -- dead after conv
//   [512K, +32M)     : A0 bf16 65536x256 (aliases agg; used after conv)
//                      A2 reuses A0 after lstm stage 0
//   [512K+32M, +64M) : A1 bf16 65536x256
// ---------------------------------------------------------------------------
extern "C" void kernel_launch(void* const* d_in, const int* in_sizes, int n_in,
                              void* d_out, int out_size, void* d_ws, size_t ws_size,
                              hipStream_t stream)
{
    const float* x    = (const float*)d_in[0];
    const int*   ei   = (const int*)d_in[1];
    const float* ea   = (const float*)d_in[2];
    const int*   samp = (const int*)d_in[3];
    const float* gm   = (const float*)d_in[4];
    const float* Wm   = (const float*)d_in[5];
    const float* bm   = (const float*)d_in[6];
    const float* Wn   = (const float*)d_in[7];
    const float* bn   = (const float*)d_in[8];
    const float* We   = (const float*)d_in[9];
    const float* be   = (const float*)d_in[10];
    const float* Wih0 = (const float*)d_in[11];
    const float* Whh0 = (const float*)d_in[12];
    const float* bih0 = (const float*)d_in[13];
    const float* bhh0 = (const float*)d_in[14];
    const float* Wih1 = (const float*)d_in[15];
    const float* Whh1 = (const float*)d_in[16];
    const float* bih1 = (const float*)d_in[17];
    const float* bhh1 = (const float*)d_in[18];
    const float* Wd1  = (const float*)d_in[19];
    const float* bd1  = (const float*)d_in[20];
    const float* Wd2  = (const float*)d_in[21];
    const float* bd2  = (const float*)d_in[22];

    char* ws = (char*)d_ws;
    __hip_bfloat16* Wt0 = (__hip_bfloat16*)ws;                  // 256 KiB
    __hip_bfloat16* Wt1 = (__hip_bfloat16*)(ws + 262144);       // 256 KiB
    float*          agg = (float*)(ws + 524288);                // 64 MiB
    __hip_bfloat16* A0  = (__hip_bfloat16*)(ws + 524288);       // 32 MiB (after conv)
    __hip_bfloat16* A2  = (__hip_bfloat16*)(ws + 524288);       // reuses A0 after lstm0
    __hip_bfloat16* A1  = (__hip_bfloat16*)(ws + 524288 + 33554432);

    float* out  = (float*)d_out;
    float* o_nc = out;                 // 65536*64
    float* o_h1 = out + 4194304;       // 65536*128
    float* o_c1 = out + 12582912;
    float* o_h2 = out + 20971520;
    float* o_c2 = out + 29360128;
    float* o_y  = out + 37748736;      // 65536*6

    hipMemsetAsync(agg, 0, 67108864, stream);
    transpose_wt<<<512, 256, 0, stream>>>(Wih0, Whh0, Wt0);
    transpose_wt<<<512, 256, 0, stream>>>(Wih1, Whh1, Wt1);
    edge_kernel<<<2048, 256, 0, stream>>>(x, ei, ea, Wm, bm, agg);
    conv_kernel<<<512, 256, 0, stream>>>(x, agg, samp, Wn, bn, o_nc);
    enc_kernel<<<1024, 256, 0, stream>>>(o_nc, gm, We, be, A0, A1);
    lstm_kernel<<<1024, 256, 0, stream>>>(A0, Wt0, bih0, bhh0, gm, o_h1, o_c1, A1, 0);
    lstm_kernel<<<1024, 256, 0, stream>>>(A1, Wt1, bih1, bhh1, gm, o_h2, o_c2, A2, 1);
    dec_kernel<<<1024, 256, 0, stream>>>(A2, Wd1, bd1, Wd2, bd2, o_y);
}